// Round 4
// baseline (355738.232 us; speedup 1.0000x reference)
//
#include <hip/hip_runtime.h>

// ACT RNN, T=8192, IO=32, H=256, M=4, EPS=0.01. All f32 in/out.
// Round 12: DVFS experiment. Evidence: identical act_chain dispatches span
// 12.8->53 ms (4.2x) with identical memory counters and clock-ratio-invariant
// VALUBusy -> the single-CU workload is being downclocked (activity-based
// DVFS). Fix attempt: grid = 1 real block + 256 register-only "heater" blocks
// (2 waves each, independent FMA chains) that keep aggregate CU activity high
// so the governor holds boost. Heaters poll a device-scope monotonic counter
// that block 0 bumps at exit (race-free across graph replays; iteration cap
// as a safety net; no writes except the counter by block 0).
// act_chain compute body is byte-for-byte round 11 (passed, absmax 1.95e-3).
// ws = 8.45 MB + 8B counter at +12 MiB (ws_size 16 MiB).

#define T_  8192
#define IO_ 32
#define H_  256

typedef __attribute__((ext_vector_type(2))) float v2f;

template<int CTRL>
__device__ __forceinline__ float dpp_addf(float x) {
    int xi = __builtin_bit_cast(int, x);
    int d = __builtin_amdgcn_update_dpp(xi, xi, CTRL, 0xF, 0xF, false);
    return x + __builtin_bit_cast(float, d);
}
template<int CTRL>
__device__ __forceinline__ float dpp_get(float x) {
    int xi = __builtin_bit_cast(int, x);
    int d = __builtin_amdgcn_update_dpp(xi, xi, CTRL, 0xF, 0xF, false);
    return __builtin_bit_cast(float, d);
}
// LDS-only barrier: flush DS ops, sync, but do NOT drain vmcnt (global
// prefetch/stores stay in flight across it).
__device__ __forceinline__ void bar_lds() {
    asm volatile("s_waitcnt lgkmcnt(0)\n\ts_barrier" ::: "memory");
    __builtin_amdgcn_sched_barrier(0);
}

// 256x256 matvec slice + all-DPP rotation reduce.
// Lane (w, grp=l>>4, m=l&15): slots k hold row rbase+((k+m)&7), cols
// [m*16, m*16+16). Returns full row-sum of row rbase+(m&7) (dup at m, m+8).
__device__ __forceinline__ float mv_reduce(const v2f (&wt)[8][8], const v2f (&sc)[8]) {
    float v[8];
    #pragma unroll
    for (int k = 0; k < 8; ++k) {
        v2f a = wt[k][0] * sc[0];
        #pragma unroll
        for (int q = 1; q < 8; ++q) a += wt[k][q] * sc[q];
        v[k] = a.x + a.y;
    }
    // stage1: ror8 fold (m <-> m+8; rho ignores bit3 of m) — direction-free
    #pragma unroll
    for (int k = 0; k < 8; ++k) v[k] = dpp_addf<0x128>(v[k]);
    // stage2: ror4 with slot k <- k+4 (+-4 == 4 mod 8) — direction-free
    v[0] += dpp_get<0x124>(v[4]);
    v[1] += dpp_get<0x124>(v[5]);
    v[2] += dpp_get<0x124>(v[6]);
    v[3] += dpp_get<0x124>(v[7]);
    // stage3: rorN from slot N (rows: (N + (m-N))&7 == m&7)
    v[0] += dpp_get<0x121>(v[1]);
    v[0] += dpp_get<0x122>(v[2]);
    v[0] += dpp_get<0x123>(v[3]);
    return v[0];
}

// ---------------- k_prep: WxpT[io][h] = (Wx[:,:H]@Wp)^T, c = Wx[:,:H]@bp + b
__global__ void k_prep(const float* __restrict__ Wx,
                       const float* __restrict__ Wp,
                       const float* __restrict__ bp,
                       const float* __restrict__ b,
                       float* __restrict__ WxpT, float* __restrict__ cvec) {
    int h = blockIdx.x;           // 0..255
    int t = threadIdx.x;          // 0..63
    __shared__ float wxrow[H_];
    for (int j = t; j < H_; j += 64) wxrow[j] = Wx[h * (H_ + 1) + j];
    __syncthreads();
    if (t < IO_) {
        float acc = 0.0f;
        for (int j = 0; j < H_; ++j) acc += wxrow[j] * Wp[j * IO_ + t];
        WxpT[t * H_ + h] = acc;
    } else if (t == IO_) {
        float acc = b[h];
        for (int j = 0; j < H_; ++j) acc += wxrow[j] * bp[j];
        cvec[h] = acc;
    }
}

// ---------------- k_u: U[t][h] = (WxpT^T x_t + c) * 2*log2(e) ----------------
__global__ void k_u(const float* __restrict__ x,
                    const float* __restrict__ WxpT,
                    const float* __restrict__ cvec,
                    float* __restrict__ U) {
    int t0 = blockIdx.x * 8;
    int tid = threadIdx.x;        // 256
    __shared__ float xsf[8 * IO_];
    xsf[tid] = x[(size_t)t0 * IO_ + tid];
    __syncthreads();
    int h = tid;
    float base = cvec[h];
    const float L2E2 = 2.8853900817779268f;
    for (int tt = 0; tt < 8; ++tt) {
        float acc = base;
        #pragma unroll
        for (int io = 0; io < IO_; ++io)
            acc += WxpT[io * H_ + h] * xsf[tt * IO_ + io];
        U[(size_t)(t0 + tt) * H_ + h] = acc * L2E2;
    }
}

// ---------------- act_chain (block 0) + DVFS heaters (blocks 1..256) --------
__global__ __launch_bounds__(512, 2) void act_chain(
    const float* __restrict__ Ws,
    const float* __restrict__ Wx,
    const float* __restrict__ wh,
    const float* __restrict__ bh1,
    const float* __restrict__ h0,
    float* __restrict__ UAcc,
    float* __restrict__ cumArr,
    float* __restrict__ pc_out,
    unsigned* __restrict__ hb)
{
    if (blockIdx.x != 0) {
        // ---- heater: 2 waves of register-only FMA; exit when block 0 bumps hb
        if (threadIdx.x >= 128) return;
        unsigned c0 = __hip_atomic_load(hb, __ATOMIC_RELAXED,
                                        __HIP_MEMORY_SCOPE_AGENT);
        float a = 1.0f + (float)threadIdx.x, b2 = 1.5f, c = 2.5f, d = 3.5f;
        #pragma unroll 1
        for (int it = 0; it < 65536; ++it) {           // cap: safety net only
            #pragma unroll 1
            for (int j = 0; j < 256; ++j) {            // ~1-2 us between polls
                a  = __builtin_fmaf(a,  1.0000001f,  1.0e-7f);
                b2 = __builtin_fmaf(b2, 0.9999999f,  2.0e-7f);
                c  = __builtin_fmaf(c,  1.0000002f, -1.0e-7f);
                d  = __builtin_fmaf(d,  0.9999998f,  3.0e-7f);
            }
            if (__hip_atomic_load(hb, __ATOMIC_RELAXED,
                                  __HIP_MEMORY_SCOPE_AGENT) != c0) break;
        }
        asm volatile("" :: "v"(a), "v"(b2), "v"(c), "v"(d));  // keep loop live
        return;
    }

    // s layout: 16 chunks of 16 floats, chunk stride 20 floats
    __shared__ __align__(16) float sbuf[2][320];
    __shared__ __align__(16) float plds[2][8];

    const int tid = threadIdx.x;
    const int w   = tid >> 6;                 // wave 0..7
    const int l   = tid & 63;
    const int m   = l & 15;                   // col-chunk: cols [m*16, m*16+16)
    const int rbase = w * 32 + ((l >> 4) & 3) * 8;
    const int r_own = rbase + (m & 7);        // row owned after reduce (dup m, m+8)
    const int swidx = (r_own >> 4) * 20 + (r_own & 15);
    const bool pub  = (l & 8) == 0;

    const float L2E  = 1.4426950408889634f;
    const float L2E2 = 2.8853900817779268f;

    // Ws tile, diagonal row scramble rho(k,m)=(k+m)&7, prescaled by 2*log2(e)
    v2f wt[8][8];
    #pragma unroll
    for (int k = 0; k < 8; ++k) {
        const int rk = rbase + ((k + m) & 7);
        const float4* s4 = (const float4*)(Ws + (size_t)rk * H_ + m * 16);
        #pragma unroll
        for (int q = 0; q < 4; ++q) {
            float4 f = s4[q];
            wt[k][2 * q]     = (v2f){f.x * L2E2, f.y * L2E2};
            wt[k][2 * q + 1] = (v2f){f.z * L2E2, f.w * L2E2};
        }
    }

    const float wlf = Wx[(size_t)r_own * (H_ + 1) + H_] * L2E2;  // first-step flag wt
    const float whp = wh[r_own] * (-L2E);     // -log2(e) sigmoid prescale
    const float bhp = -bh1[0] * L2E;
    const float thresh = 0.99f;

    // init: zh = scaled Ws @ h0 (h0 read direct from global)
    float zh;
    {
        v2f sc[8];
        const float4* hp = (const float4*)(h0 + m * 16);
        #pragma unroll
        for (int q = 0; q < 4; ++q) {
            float4 f = hp[q];
            sc[2 * q]     = (v2f){f.x, f.y};
            sc[2 * q + 1] = (v2f){f.z, f.w};
        }
        zh = mv_reduce(wt, sc);
    }

    float pc = 0.0f;
    float un_cur = UAcc[r_own];        // U[0][r_own] (pre-scaled by 2*log2 e)
    float u0_cur = un_cur + wlf;

    // one ponder round: s=tanh(in); publish; halting partial; bar; read; z; p
    auto round = [&](int WB, int PP, float in, float& z, float& p) -> float {
        float e = __builtin_amdgcn_exp2f(in);
        float s = __builtin_fmaf(-2.0f, __builtin_amdgcn_rcpf(e + 1.0f), 1.0f);
        if (pub) sbuf[WB][swidx] = s;
        float part = whp * s;                 // 8-row run: lane15 covers lanes 8..15
        part = dpp_addf<0x121>(part);         // ror1
        part = dpp_addf<0x122>(part);         // ror2
        part = dpp_addf<0x124>(part);         // ror4
        part = dpp_addf<0x142>(part);         // row_bcast15
        part = dpp_addf<0x143>(part);         // row_bcast31 -> lane63 = wave total
        if (l == 63) plds[PP][w] = part;
        bar_lds();
        const float4* sp = (const float4*)(&sbuf[WB][m * 20]);
        float4 f0 = sp[0], f1 = sp[1], f2 = sp[2], f3 = sp[3];
        const float4* pr = (const float4*)(&plds[PP][0]);
        float4 qa = pr[0], qb = pr[1];
        v2f sc[8] = {{f0.x, f0.y}, {f0.z, f0.w}, {f1.x, f1.y}, {f1.z, f1.w},
                     {f2.x, f2.y}, {f2.z, f2.w}, {f3.x, f3.y}, {f3.z, f3.w}};
        z = mv_reduce(wt, sc);
        float dot = ((qa.x + qa.y) + (qa.z + qa.w)) +
                    ((qb.x + qb.y) + (qb.z + qb.w));
        p = __builtin_amdgcn_rcpf(1.0f + __builtin_amdgcn_exp2f(dot + bhp));
        return s;
    };

    #pragma unroll 1
    for (int t = 0; t < T_; ++t) {
        const int tn = (t + 1 < T_) ? t + 1 : t;
        const float un_nxt = UAcc[(size_t)tn * H_ + r_own];   // prefetch next U

        // rounds 0,1 unconditional, straight-line (no halt branch on the chain)
        float z0, p0, z1, p1;
        float s0 = round(0, 0, zh + u0_cur, z0, p0);
        float s1 = round(1, 1, z0 + un_cur, z1, p1);

        bool  halt0  = p0 > thresh;
        float w0     = halt0 ? 1.0f : p0;
        bool  still1 = !halt0;
        float cum1   = w0;
        bool  halt1  = (cum1 + p1 > thresh);
        float w1     = still1 ? (halt1 ? 1.0f - cum1 : p1) : 0.0f;
        float accs   = __builtin_fmaf(w1, s1, w0 * s0);
        float zacc   = __builtin_fmaf(w1, z1, w0 * z0);
        float cum    = cum1 + w1;
        float nup    = still1 ? 2.0f : 1.0f;
        float rem    = halt0 ? 1.0f : (halt1 ? 1.0f - cum1 : 0.0f);

        if (still1 && !halt1) {               // rare: rounds 2,3 (both run: parity)
            float z2, p2, z3, p3;
            float s2 = round(0, 0, z1 + un_cur, z2, p2);
            bool  halt2 = (cum + p2 > thresh);
            float w2    = halt2 ? 1.0f - cum : p2;
            float rem2  = halt2 ? 1.0f - cum : 0.0f;
            accs = __builtin_fmaf(w2, s2, accs);
            zacc = __builtin_fmaf(w2, z2, zacc);
            float cum3  = cum + w2;
            bool  still3 = !halt2;
            float s3 = round(1, 1, z2 + un_cur, z3, p3);
            float w3 = still3 ? (1.0f - cum3) : 0.0f;   // n==3 forces halt
            accs = __builtin_fmaf(w3, s3, accs);
            zacc = __builtin_fmaf(w3, z3, zacc);
            rem  = rem2 + w3;
            cum  = cum3 + w3;
            nup  = still3 ? 4.0f : 3.0f;
        }

        pc = (pc + nup + rem) * (1.0f / (float)T_);
        zh = zacc;                            // Z(h') by linearity — no LDS trip
        if (pub) UAcc[(size_t)t * H_ + r_own] = accs;    // acc_s over dead U row
        if (tid == 0) cumArr[t] = cum;
        un_cur = un_nxt;
        u0_cur = un_nxt + wlf;
    }
    if (tid == 0) {
        pc_out[0] = pc;
        __hip_atomic_fetch_add(hb, 1u, __ATOMIC_RELEASE,
                               __HIP_MEMORY_SCOPE_AGENT);   // release heaters
    }
}

// ---------------- k_out: ys[t] = Wo@acc_s[t] + cum[t]*bo ----------------
__global__ void k_out(const float* __restrict__ AccS,
                      const float* __restrict__ Wo,
                      const float* __restrict__ bo,
                      const float* __restrict__ cumArr,
                      float* __restrict__ ys) {
    int t0 = blockIdx.x * 8;
    int tid = threadIdx.x;   // 256
    __shared__ float wo[IO_ * 257];
    __shared__ float as[8 * 260];
    for (int i = tid; i < IO_ * H_; i += 256) {
        int o = i / H_, h = i % H_;
        wo[o * 257 + h] = Wo[i];
    }
    for (int i = tid; i < 8 * H_; i += 256) {
        int tt = i / H_, h = i % H_;
        as[tt * 260 + h] = AccS[(size_t)t0 * H_ + i];
    }
    __syncthreads();
    int tt = tid >> 5, o = tid & 31;
    float acc = cumArr[t0 + tt] * bo[o];
    #pragma unroll 4
    for (int h = 0; h < H_; ++h) acc += wo[o * 257 + h] * as[tt * 260 + h];
    ys[(size_t)(t0 + tt) * IO_ + o] = acc;
}

extern "C" void kernel_launch(void* const* d_in, const int* in_sizes, int n_in,
                              void* d_out, int out_size, void* d_ws, size_t ws_size,
                              hipStream_t stream) {
    const float* x  = (const float*)d_in[0];
    const float* h0 = (const float*)d_in[1];
    const float* Wp = (const float*)d_in[2];
    const float* bp = (const float*)d_in[3];
    const float* Wx = (const float*)d_in[4];
    const float* Ws = (const float*)d_in[5];
    const float* b  = (const float*)d_in[6];
    const float* wh = (const float*)d_in[7];
    const float* bh = (const float*)d_in[8];
    const float* Wo = (const float*)d_in[9];
    const float* bo = (const float*)d_in[10];
    float* out = (float*)d_out;   // f32: ys[8192*32] then pc

    char* ws = (char*)d_ws;
    float* WxpT = (float*)ws;                                    //  32 KB
    float* cvec = (float*)(ws + 32768);                          //   1 KB
    float* cumA = (float*)(ws + 33792);                          //  32 KB
    float* UAcc = (float*)(ws + 66560);                          //   8 MB f32
    unsigned* hb = (unsigned*)(ws + 12 * 1024 * 1024);           //   8 B counter
    // total ws use: 8.45 MB + counter (AccS aliases UAcc in place)

    k_prep<<<H_, 64, 0, stream>>>(Wx, Wp, bp, b, WxpT, cvec);
    k_u<<<T_ / 8, 256, 0, stream>>>(x, WxpT, cvec, UAcc);
    act_chain<<<257, 512, 0, stream>>>(Ws, Wx, wh, bh, h0, UAcc, cumA,
                                       out + (size_t)T_ * IO_, hb);
    k_out<<<T_ / 8, 256, 0, stream>>>(UAcc, Wo, bo, cumA, out);
}

// Round 5
// 12035.217 us; speedup vs baseline: 29.5581x; 29.5581x over previous
//
#include <hip/hip_runtime.h>

// ACT RNN, T=8192, IO=32, H=256, M=4, EPS=0.01. All f32 in/out.
// Round 13: revert act_chain compute body to the round-8 verified best
// (scored 12.10 ms) + LOW-POWER duty-cycled DVFS heater experiment.
// Clock evidence: VALUBusy-derived cycles/timestep (~1200) matches the issue
// model, but wall time implies ~700-800 MHz effective clock. Round-12's
// full-power heaters tripped the power brake (355 ms). This round: 64 heater
// blocks x 1 wave at ~50% duty (256-FMA burst + s_sleep), ~9% of round-12
// heater power, 25% CU coverage; exit on flag OR 15 ms s_memrealtime cap.
// ws = 8.45 MB + 8B counter at +12 MiB (ws_size 16 MiB).

#define T_  8192
#define IO_ 32
#define H_  256

typedef __attribute__((ext_vector_type(2))) float v2f;

template<int CTRL>
__device__ __forceinline__ float dpp_addf(float x) {
    int xi = __builtin_bit_cast(int, x);
    int d = __builtin_amdgcn_update_dpp(xi, xi, CTRL, 0xF, 0xF, false);
    return x + __builtin_bit_cast(float, d);
}

// ---------------- k_prep: WxpT[io][h] = (Wx[:,:H]@Wp)^T, c = Wx[:,:H]@bp + b
__global__ void k_prep(const float* __restrict__ Wx,
                       const float* __restrict__ Wp,
                       const float* __restrict__ bp,
                       const float* __restrict__ b,
                       float* __restrict__ WxpT, float* __restrict__ cvec) {
    int h = blockIdx.x;           // 0..255
    int t = threadIdx.x;          // 0..63
    __shared__ float wxrow[H_];
    for (int j = t; j < H_; j += 64) wxrow[j] = Wx[h * (H_ + 1) + j];
    __syncthreads();
    if (t < IO_) {
        float acc = 0.0f;
        for (int j = 0; j < H_; ++j) acc += wxrow[j] * Wp[j * IO_ + t];
        WxpT[t * H_ + h] = acc;
    } else if (t == IO_) {
        float acc = b[h];
        for (int j = 0; j < H_; ++j) acc += wxrow[j] * bp[j];
        cvec[h] = acc;
    }
}

// ---------------- k_u: U[t][h] = WxpT^T x_t + c  (f32) ----------------
__global__ void k_u(const float* __restrict__ x,
                    const float* __restrict__ WxpT,
                    const float* __restrict__ cvec,
                    float* __restrict__ U) {
    int t0 = blockIdx.x * 8;
    int tid = threadIdx.x;        // 256
    __shared__ float xsf[8 * IO_];
    xsf[tid] = x[(size_t)t0 * IO_ + tid];
    __syncthreads();
    int h = tid;
    float base = cvec[h];
    for (int tt = 0; tt < 8; ++tt) {
        float acc = base;
        #pragma unroll
        for (int io = 0; io < IO_; ++io)
            acc += WxpT[io * H_ + h] * xsf[tt * IO_ + io];
        U[(size_t)(t0 + tt) * H_ + h] = acc;
    }
}

// ---------------- act_chain (block 0) + gentle heaters (blocks 1..64) -------
// Block 0 body is byte-identical to the round-8 verified kernel (12.10 ms).
__global__ __launch_bounds__(512, 2) void act_chain(
    const float* __restrict__ Ws,
    const float* __restrict__ Wx,
    const float* __restrict__ wh,
    const float* __restrict__ bh1,
    const float* __restrict__ h0,
    float* __restrict__ UAcc,
    float* __restrict__ cumArr,
    float* __restrict__ pc_out,
    unsigned* __restrict__ hb)
{
    if (blockIdx.x != 0) {
        // ---- heater: 1 wave, ~50% duty FMA; exit on flag or 15 ms realtime
        if (threadIdx.x >= 64) return;
        unsigned c0 = __hip_atomic_load(hb, __ATOMIC_RELAXED,
                                        __HIP_MEMORY_SCOPE_AGENT);
        long long rt0 = __builtin_amdgcn_s_memrealtime();   // ~100 MHz ref clk
        float a = 1.0f + (float)threadIdx.x, b2 = 1.5f, c = 2.5f, d = 3.5f;
        #pragma unroll 1
        while (true) {
            #pragma unroll 1
            for (int j = 0; j < 64; ++j) {           // ~512 busy cycles
                a  = __builtin_fmaf(a,  1.0000001f,  1.0e-7f);
                b2 = __builtin_fmaf(b2, 0.9999999f,  2.0e-7f);
                c  = __builtin_fmaf(c,  1.0000002f, -1.0e-7f);
                d  = __builtin_fmaf(d,  0.9999998f,  3.0e-7f);
            }
            __builtin_amdgcn_s_sleep(8);             // ~512 idle cycles
            if (__hip_atomic_load(hb, __ATOMIC_RELAXED,
                                  __HIP_MEMORY_SCOPE_AGENT) != c0) break;
            if (__builtin_amdgcn_s_memrealtime() - rt0 > 1500000) break; // 15ms
        }
        asm volatile("" :: "v"(a), "v"(b2), "v"(c), "v"(d));  // keep live
        return;
    }

    __shared__ __align__(16) float sbuf[2][4 * 68];
    __shared__ __align__(16) float plds[2][8];

    const int tid = threadIdx.x;
    const int w   = tid >> 6;        // wave 0..7
    const int l   = tid & 63;
    const int rg  = l >> 2;          // row-group 0..15 (2 rows each)
    const int c   = l & 3;           // 64-col chunk 0..3
    const int rowbase = w * 32 + rg * 2;
    const int schunk  = rowbase >> 6;         // h-write chunk
    const int soff    = rowbase & 63;

    // Ws tile: 2 rows x 64 cols as v2f[2][32] = 128 VGPRs
    v2f wt[2][32];
    #pragma unroll
    for (int r = 0; r < 2; ++r) {
        const float4* src = (const float4*)(Ws + (size_t)(rowbase + r) * H_ + c * 64);
        #pragma unroll
        for (int q = 0; q < 16; ++q) {
            float4 f = src[q];
            wt[r][2 * q]     = (v2f){f.x, f.y};
            wt[r][2 * q + 1] = (v2f){f.z, f.w};
        }
    }

    v2f wl2, whv2;
    wl2.x  = Wx[(size_t)rowbase * (H_ + 1) + H_];
    wl2.y  = Wx[(size_t)(rowbase + 1) * (H_ + 1) + H_];
    whv2.x = wh[rowbase];
    whv2.y = wh[rowbase + 1];
    const float bhf = bh1[0];
    const float thresh = 1.0f - 0.01f;
    const float L2E  = 1.4426950408889634f;   // log2(e)
    const float L2E2 = 2.8853900817779268f;   // 2*log2(e)

    if (tid < H_) sbuf[0][(tid >> 6) * 68 + (tid & 63)] = h0[tid];
    __syncthreads();

    int cur = 0, pp = 0;
    float pc = 0.0f;

    #pragma unroll 1
    for (int tg = 0; tg < T_ / 4; ++tg) {
        v2f un[4];
        #pragma unroll
        for (int k = 0; k < 4; ++k)
            un[k] = *(const v2f*)(UAcc + (size_t)(tg * 4 + k) * H_ + rowbase);

        v2f   av[4];
        float cu4[4];

        #pragma unroll
        for (int k = 0; k < 4; ++k) {
            const v2f uu1 = un[k];
            const v2f uu0 = uu1 + wl2;      // n==0: first-step flag folded in

            v2f accs = {0.f, 0.f};
            float cum = 0.0f, nup = 0.0f, remt = 0.0f;
            float sn0, sn1;

            #pragma unroll 1
            for (int n = 0; n < 4; ++n) {
                // dot: 2 rows x 64 cols, v_pk_fma_f32
                v2f acc0 = {0.f, 0.f}, acc1 = {0.f, 0.f};
                const float4* sp = (const float4*)(&sbuf[cur][c * 68]);
                #pragma unroll
                for (int q = 0; q < 16; ++q) {
                    float4 f = sp[q];
                    v2f sa = (v2f){f.x, f.y};
                    v2f sb = (v2f){f.z, f.w};
                    acc0 = acc0 + wt[0][2 * q] * sa;
                    acc0 = acc0 + wt[0][2 * q + 1] * sb;
                    acc1 = acc1 + wt[1][2 * q] * sa;
                    acc1 = acc1 + wt[1][2 * q + 1] * sb;
                }
                float y0 = acc0.x + acc0.y;
                float y1 = acc1.x + acc1.y;
                // reduce over the 4 c-lanes (quad): xor1, xor2
                y0 = dpp_addf<0xB1>(y0); y0 = dpp_addf<0x4E>(y0);
                y1 = dpp_addf<0xB1>(y1); y1 = dpp_addf<0x4E>(y1);

                v2f uu = (n == 0) ? uu0 : uu1;
                float yy0 = y0 + uu.x;
                float yy1 = y1 + uu.y;
                float e0 = __builtin_amdgcn_exp2f(yy0 * L2E2);
                float e1 = __builtin_amdgcn_exp2f(yy1 * L2E2);
                sn0 = __builtin_fmaf(-2.0f, __builtin_amdgcn_rcpf(e0 + 1.0f), 1.0f);
                sn1 = __builtin_fmaf(-2.0f, __builtin_amdgcn_rcpf(e1 + 1.0f), 1.0f);

                int nxt = cur ^ 1;
                if (c == 0)
                    *(v2f*)(&sbuf[nxt][schunk * 68 + soff]) = (v2f){sn0, sn1};

                // halting partial: quad-uniform; sum rg over row (ror4+ror8),
                // then cross-row (bcast15+bcast31) -> lane63 = wave total
                float part = __builtin_fmaf(whv2.x, sn0, whv2.y * sn1);
                part = dpp_addf<0x124>(part);   // row_ror:4
                part = dpp_addf<0x128>(part);   // row_ror:8
                part = dpp_addf<0x142>(part);   // row_bcast15
                part = dpp_addf<0x143>(part);   // row_bcast31
                if (l == 63) plds[pp][w] = part;
                __syncthreads();

                float4 pa = *(const float4*)(&plds[pp][0]);
                float4 pb = *(const float4*)(&plds[pp][4]);
                float dot = ((pa.x + pa.y) + (pa.z + pa.w)) +
                            ((pb.x + pb.y) + (pb.z + pb.w));
                pp ^= 1;
                float p = __builtin_amdgcn_rcpf(
                    1.0f + __builtin_amdgcn_exp2f(-(dot + bhf) * L2E));
                bool halt = (cum + p > thresh) || (n == 3);
                float hw = 1.0f - cum;
                float wn = halt ? hw : p;
                accs = accs + wn * (v2f){sn0, sn1};
                nup += 1.0f;
                cum += wn;
                if (halt) { remt = hw; break; }   // exact: w==0 afterwards
                cur = nxt;
            }

            pc = (pc + nup + remt) * (1.0f / (float)T_);

            int hb2 = cur ^ 1;   // dead buffer -> becomes h
            av[k]  = accs;
            cu4[k] = cum;
            if (c == 0)
                *(v2f*)(&sbuf[hb2][schunk * 68 + soff]) = accs;
            cur = hb2;
            __syncthreads();
        }

        // batched stores: acc_s in place over dead U rows, + cum
        if (c == 0) {
            #pragma unroll
            for (int k = 0; k < 4; ++k)
                *(v2f*)(UAcc + (size_t)(tg * 4 + k) * H_ + rowbase) = av[k];
        }
        if (tid == 0) {
            #pragma unroll
            for (int k = 0; k < 4; ++k) cumArr[tg * 4 + k] = cu4[k];
        }
    }
    if (tid == 0) {
        pc_out[0] = pc;
        __hip_atomic_fetch_add(hb, 1u, __ATOMIC_RELEASE,
                               __HIP_MEMORY_SCOPE_AGENT);   // release heaters
    }
}

// ---------------- k_out: ys[t] = Wo@acc_s[t] + cum[t]*bo ----------------
__global__ void k_out(const float* __restrict__ AccS,
                      const float* __restrict__ Wo,
                      const float* __restrict__ bo,
                      const float* __restrict__ cumArr,
                      float* __restrict__ ys) {
    int t0 = blockIdx.x * 8;
    int tid = threadIdx.x;   // 256
    __shared__ float wo[IO_ * 257];
    __shared__ float as[8 * 260];
    for (int i = tid; i < IO_ * H_; i += 256) {
        int o = i / H_, h = i % H_;
        wo[o * 257 + h] = Wo[i];
    }
    for (int i = tid; i < 8 * H_; i += 256) {
        int tt = i / H_, h = i % H_;
        as[tt * 260 + h] = AccS[(size_t)t0 * H_ + i];
    }
    __syncthreads();
    int tt = tid >> 5, o = tid & 31;
    float acc = cumArr[t0 + tt] * bo[o];
    #pragma unroll 4
    for (int h = 0; h < H_; ++h) acc += wo[o * 257 + h] * as[tt * 260 + h];
    ys[(size_t)(t0 + tt) * IO_ + o] = acc;
}

extern "C" void kernel_launch(void* const* d_in, const int* in_sizes, int n_in,
                              void* d_out, int out_size, void* d_ws, size_t ws_size,
                              hipStream_t stream) {
    const float* x  = (const float*)d_in[0];
    const float* h0 = (const float*)d_in[1];
    const float* Wp = (const float*)d_in[2];
    const float* bp = (const float*)d_in[3];
    const float* Wx = (const float*)d_in[4];
    const float* Ws = (const float*)d_in[5];
    const float* b  = (const float*)d_in[6];
    const float* wh = (const float*)d_in[7];
    const float* bh = (const float*)d_in[8];
    const float* Wo = (const float*)d_in[9];
    const float* bo = (const float*)d_in[10];
    float* out = (float*)d_out;   // f32: ys[8192*32] then pc

    char* ws = (char*)d_ws;
    float* WxpT = (float*)ws;                                    //  32 KB
    float* cvec = (float*)(ws + 32768);                          //   1 KB
    float* cumA = (float*)(ws + 33792);                          //  32 KB
    float* UAcc = (float*)(ws + 66560);                          //   8 MB f32
    unsigned* hb = (unsigned*)(ws + 12 * 1024 * 1024);           //   8 B counter
    // total ws use: 8.45 MB + counter (AccS aliases UAcc in place)

    k_prep<<<H_, 64, 0, stream>>>(Wx, Wp, bp, b, WxpT, cvec);
    k_u<<<T_ / 8, 256, 0, stream>>>(x, WxpT, cvec, UAcc);
    act_chain<<<65, 512, 0, stream>>>(Ws, Wx, wh, bh, h0, UAcc, cumA,
                                      out + (size_t)T_ * IO_, hb);
    k_out<<<T_ / 8, 256, 0, stream>>>(UAcc, Wo, bo, cumA, out);
}

// Round 6
// 11999.156 us; speedup vs baseline: 29.6469x; 1.0030x over previous
//
#include <hip/hip_runtime.h>

// ACT RNN, T=8192, IO=32, H=256, M=4, EPS=0.01. All f32 in/out.
// Round 14: merge of the two verified structures, pure cycle diet.
// (Round-13 heater experiment falsified the DVFS lever: occupancy x9, wall
// time unchanged -> only cycles matter.)
//  - Round-8 lane layout (2 rows x 64 cols, quad xor1+xor2 completes row sum)
//  - Round-11 round ordering + Z-linearity: tanh -> publish s -> barrier ->
//    matvec(s) -> z; zacc = sum wn*zn is next timestep's zh. No h publication:
//    2 barriers + 2 LDS publications per timestep (round 8 had 3+3).
//  - Dual accumulators per row: 32-deep pk_fma dep chain -> 16-deep.
//  - L2E2/L2E prefolded into U (k_u), Ws tile, wl, wh, bh.
//  - Branchless rounds 0-1 + rare block-uniform branch for rounds 2-3
//    (round-11 ACT weight algebra, verified exact, absmax 1.95e-3).
//  - raw "s_waitcnt lgkmcnt(0); s_barrier" (no vmcnt drain).
// ws = 8.45 MB (AccS aliases U in place; ws_size 16 MiB).

#define T_  8192
#define IO_ 32
#define H_  256

typedef __attribute__((ext_vector_type(2))) float v2f;

template<int CTRL>
__device__ __forceinline__ float dpp_addf(float x) {
    int xi = __builtin_bit_cast(int, x);
    int d = __builtin_amdgcn_update_dpp(xi, xi, CTRL, 0xF, 0xF, false);
    return x + __builtin_bit_cast(float, d);
}
// LDS-only barrier: flush DS ops, sync, do NOT drain vmcnt (global prefetch
// and fire-and-forget stores stay in flight).
__device__ __forceinline__ void bar_lds() {
    asm volatile("s_waitcnt lgkmcnt(0)\n\ts_barrier" ::: "memory");
    __builtin_amdgcn_sched_barrier(0);
}

// ---------------- k_prep: WxpT[io][h] = (Wx[:,:H]@Wp)^T, c = Wx[:,:H]@bp + b
__global__ void k_prep(const float* __restrict__ Wx,
                       const float* __restrict__ Wp,
                       const float* __restrict__ bp,
                       const float* __restrict__ b,
                       float* __restrict__ WxpT, float* __restrict__ cvec) {
    int h = blockIdx.x;           // 0..255
    int t = threadIdx.x;          // 0..63
    __shared__ float wxrow[H_];
    for (int j = t; j < H_; j += 64) wxrow[j] = Wx[h * (H_ + 1) + j];
    __syncthreads();
    if (t < IO_) {
        float acc = 0.0f;
        for (int j = 0; j < H_; ++j) acc += wxrow[j] * Wp[j * IO_ + t];
        WxpT[t * H_ + h] = acc;
    } else if (t == IO_) {
        float acc = b[h];
        for (int j = 0; j < H_; ++j) acc += wxrow[j] * bp[j];
        cvec[h] = acc;
    }
}

// ---------------- k_u: U[t][h] = (WxpT^T x_t + c) * 2*log2(e) ----------------
__global__ void k_u(const float* __restrict__ x,
                    const float* __restrict__ WxpT,
                    const float* __restrict__ cvec,
                    float* __restrict__ U) {
    int t0 = blockIdx.x * 8;
    int tid = threadIdx.x;        // 256
    __shared__ float xsf[8 * IO_];
    xsf[tid] = x[(size_t)t0 * IO_ + tid];
    __syncthreads();
    int h = tid;
    float base = cvec[h];
    const float L2E2 = 2.8853900817779268f;
    for (int tt = 0; tt < 8; ++tt) {
        float acc = base;
        #pragma unroll
        for (int io = 0; io < IO_; ++io)
            acc += WxpT[io * H_ + h] * xsf[tt * IO_ + io];
        U[(size_t)(t0 + tt) * H_ + h] = acc * L2E2;
    }
}

// ---------------- act_chain ----------------
__global__ __launch_bounds__(512, 2) void act_chain(
    const float* __restrict__ Ws,
    const float* __restrict__ Wx,
    const float* __restrict__ wh,
    const float* __restrict__ bh1,
    const float* __restrict__ h0,
    float* __restrict__ UAcc,
    float* __restrict__ cumArr,
    float* __restrict__ pc_out)
{
    __shared__ __align__(16) float sbuf[2][4 * 68];
    __shared__ __align__(16) float plds[2][8];

    const int tid = threadIdx.x;
    const int w   = tid >> 6;        // wave 0..7
    const int l   = tid & 63;
    const int rg  = l >> 2;          // row-group 0..15 (2 rows each)
    const int c   = l & 3;           // 64-col chunk 0..3
    const int rowbase = w * 32 + rg * 2;
    const int schunk  = rowbase >> 6;
    const int soff    = rowbase & 63;

    const float L2E  = 1.4426950408889634f;   // log2(e)
    const float L2E2 = 2.8853900817779268f;   // 2*log2(e)

    // Ws tile: 2 rows x 64 cols as v2f[2][32], prescaled by 2*log2(e)
    v2f wt[2][32];
    #pragma unroll
    for (int r = 0; r < 2; ++r) {
        const float4* src = (const float4*)(Ws + (size_t)(rowbase + r) * H_ + c * 64);
        #pragma unroll
        for (int q = 0; q < 16; ++q) {
            float4 f = src[q];
            wt[r][2 * q]     = (v2f){f.x * L2E2, f.y * L2E2};
            wt[r][2 * q + 1] = (v2f){f.z * L2E2, f.w * L2E2};
        }
    }

    v2f wl2, whp2;
    wl2.x  = Wx[(size_t)rowbase * (H_ + 1) + H_] * L2E2;       // first-step flag
    wl2.y  = Wx[(size_t)(rowbase + 1) * (H_ + 1) + H_] * L2E2;
    whp2.x = wh[rowbase]     * (-L2E);                          // sigmoid prescale
    whp2.y = wh[rowbase + 1] * (-L2E);
    const float bhp = -bh1[0] * L2E;
    const float thresh = 1.0f - 0.01f;

    // matvec of a 64-float column chunk (16 float4s) + quad reduce.
    // Dual accumulators halve the dependent-fma chain (16-deep).
    auto matvec = [&](const float4* sp) -> v2f {
        v2f a0a = {0.f, 0.f}, a0b = {0.f, 0.f};
        v2f a1a = {0.f, 0.f}, a1b = {0.f, 0.f};
        #pragma unroll
        for (int q = 0; q < 16; ++q) {
            float4 f = sp[q];
            v2f sa = (v2f){f.x, f.y};
            v2f sb = (v2f){f.z, f.w};
            a0a = a0a + wt[0][2 * q]     * sa;
            a0b = a0b + wt[0][2 * q + 1] * sb;
            a1a = a1a + wt[1][2 * q]     * sa;
            a1b = a1b + wt[1][2 * q + 1] * sb;
        }
        v2f t0 = a0a + a0b, t1 = a1a + a1b;
        float y0 = t0.x + t0.y;
        float y1 = t1.x + t1.y;
        y0 = dpp_addf<0xB1>(y0); y0 = dpp_addf<0x4E>(y0);   // quad xor1, xor2
        y1 = dpp_addf<0xB1>(y1); y1 = dpp_addf<0x4E>(y1);
        return (v2f){y0, y1};
    };

    // prologue: zh = scaled Ws @ h0 (chunk read direct from global)
    v2f zh;
    {
        float4 hbuf[16];
        const float4* hp = (const float4*)(h0 + c * 64);
        #pragma unroll
        for (int q = 0; q < 16; ++q) hbuf[q] = hp[q];
        zh = matvec(hbuf);
    }

    float pc = 0.0f;
    v2f un = *(const v2f*)(UAcc + rowbase);   // U[0], prescaled by 2*log2(e)

    // one ponder round: s = tanh(in); publish; halting partial; barrier;
    // matvec(s) -> z; read plds -> p.  WB/PP are compile-time at call sites.
    auto round = [&](int WB, int PP, v2f in, v2f& z, float& p) -> v2f {
        float e0 = __builtin_amdgcn_exp2f(in.x);
        float e1 = __builtin_amdgcn_exp2f(in.y);
        float s0 = __builtin_fmaf(-2.0f, __builtin_amdgcn_rcpf(e0 + 1.0f), 1.0f);
        float s1 = __builtin_fmaf(-2.0f, __builtin_amdgcn_rcpf(e1 + 1.0f), 1.0f);
        if (c == 0) *(v2f*)(&sbuf[WB][schunk * 68 + soff]) = (v2f){s0, s1};
        // halting partial (quad-uniform): ror4+ror8 over row-groups,
        // bcast15+bcast31 -> lane63 = wave total (verified round 8)
        float part = __builtin_fmaf(whp2.x, s0, whp2.y * s1);
        part = dpp_addf<0x124>(part);   // row_ror:4
        part = dpp_addf<0x128>(part);   // row_ror:8
        part = dpp_addf<0x142>(part);   // row_bcast15
        part = dpp_addf<0x143>(part);   // row_bcast31
        if (l == 63) plds[PP][w] = part;
        bar_lds();
        z = matvec((const float4*)(&sbuf[WB][c * 68]));
        float4 pa = *(const float4*)(&plds[PP][0]);
        float4 pb = *(const float4*)(&plds[PP][4]);
        float dot = ((pa.x + pa.y) + (pa.z + pa.w)) +
                    ((pb.x + pb.y) + (pb.z + pb.w));
        p = __builtin_amdgcn_rcpf(1.0f + __builtin_amdgcn_exp2f(dot + bhp));
        return (v2f){s0, s1};
    };

    #pragma unroll 1
    for (int t = 0; t < T_; ++t) {
        const int tn = (t + 1 < T_) ? t + 1 : t;
        const v2f un_nxt = *(const v2f*)(UAcc + (size_t)tn * H_ + rowbase);

        // rounds 0,1 unconditional straight-line
        v2f z0, z1;
        float p0, p1;
        v2f s0 = round(0, 0, zh + un + wl2, z0, p0);
        v2f s1 = round(1, 1, z0 + un,       z1, p1);

        bool  halt0  = p0 > thresh;
        float w0     = halt0 ? 1.0f : p0;
        bool  still1 = !halt0;
        float cum1   = w0;
        bool  halt1  = (cum1 + p1 > thresh);
        float w1     = still1 ? (halt1 ? 1.0f - cum1 : p1) : 0.0f;
        v2f   accs   = w0 * s0 + w1 * s1;
        v2f   zacc   = w0 * z0 + w1 * z1;
        float cum    = cum1 + w1;
        float nup    = still1 ? 2.0f : 1.0f;
        float rem    = halt0 ? 1.0f : (halt1 ? 1.0f - cum1 : 0.0f);

        if (still1 && !halt1) {               // rare, block-uniform: rounds 2,3
            v2f z2, z3;
            float p2, p3;
            v2f s2 = round(0, 0, z1 + un, z2, p2);
            bool  halt2 = (cum + p2 > thresh);
            float w2    = halt2 ? 1.0f - cum : p2;
            float rem2  = halt2 ? 1.0f - cum : 0.0f;
            accs = accs + w2 * s2;
            zacc = zacc + w2 * z2;
            float cum3   = cum + w2;
            bool  still3 = !halt2;
            v2f s3 = round(1, 1, z2 + un, z3, p3);
            float w3 = still3 ? (1.0f - cum3) : 0.0f;   // n==3 forces halt
            accs = accs + w3 * s3;
            zacc = zacc + w3 * z3;
            rem  = rem2 + w3;
            cum  = cum3 + w3;
            nup  = still3 ? 4.0f : 3.0f;
        }

        pc = (pc + nup + rem) * (1.0f / (float)T_);
        zh = zacc;                            // Z(h') by linearity — no LDS trip
        if (c == 0) *(v2f*)(UAcc + (size_t)t * H_ + rowbase) = accs;
        if (tid == 0) cumArr[t] = cum;
        un = un_nxt;
    }
    if (tid == 0) pc_out[0] = pc;
}

// ---------------- k_out: ys[t] = Wo@acc_s[t] + cum[t]*bo ----------------
__global__ void k_out(const float* __restrict__ AccS,
                      const float* __restrict__ Wo,
                      const float* __restrict__ bo,
                      const float* __restrict__ cumArr,
                      float* __restrict__ ys) {
    int t0 = blockIdx.x * 8;
    int tid = threadIdx.x;   // 256
    __shared__ float wo[IO_ * 257];
    __shared__ float as[8 * 260];
    for (int i = tid; i < IO_ * H_; i += 256) {
        int o = i / H_, h = i % H_;
        wo[o * 257 + h] = Wo[i];
    }
    for (int i = tid; i < 8 * H_; i += 256) {
        int tt = i / H_, h = i % H_;
        as[tt * 260 + h] = AccS[(size_t)t0 * H_ + i];
    }
    __syncthreads();
    int tt = tid >> 5, o = tid & 31;
    float acc = cumArr[t0 + tt] * bo[o];
    #pragma unroll 4
    for (int h = 0; h < H_; ++h) acc += wo[o * 257 + h] * as[tt * 260 + h];
    ys[(size_t)(t0 + tt) * IO_ + o] = acc;
}

extern "C" void kernel_launch(void* const* d_in, const int* in_sizes, int n_in,
                              void* d_out, int out_size, void* d_ws, size_t ws_size,
                              hipStream_t stream) {
    const float* x  = (const float*)d_in[0];
    const float* h0 = (const float*)d_in[1];
    const float* Wp = (const float*)d_in[2];
    const float* bp = (const float*)d_in[3];
    const float* Wx = (const float*)d_in[4];
    const float* Ws = (const float*)d_in[5];
    const float* b  = (const float*)d_in[6];
    const float* wh = (const float*)d_in[7];
    const float* bh = (const float*)d_in[8];
    const float* Wo = (const float*)d_in[9];
    const float* bo = (const float*)d_in[10];
    float* out = (float*)d_out;   // f32: ys[8192*32] then pc

    char* ws = (char*)d_ws;
    float* WxpT = (float*)ws;                                    //  32 KB
    float* cvec = (float*)(ws + 32768);                          //   1 KB
    float* cumA = (float*)(ws + 33792);                          //  32 KB
    float* UAcc = (float*)(ws + 66560);                          //   8 MB f32
    // total ws use: 8.45 MB (AccS aliases UAcc in place)

    k_prep<<<H_, 64, 0, stream>>>(Wx, Wp, bp, b, WxpT, cvec);
    k_u<<<T_ / 8, 256, 0, stream>>>(x, WxpT, cvec, UAcc);
    act_chain<<<1, 512, 0, stream>>>(Ws, Wx, wh, bh, h0, UAcc, cumA,
                                     out + (size_t)T_ * IO_);
    k_out<<<T_ / 8, 256, 0, stream>>>(UAcc, Wo, bo, cumA, out);
}

// Round 7
// 11754.792 us; speedup vs baseline: 30.2633x; 1.0208x over previous
//
#include <hip/hip_runtime.h>

// ACT RNN, T=8192, IO=32, H=256, M=4, EPS=0.01. All f32 in/out.
// Round 15: chain-shortening pass on the round-14 verified base (11.999 ms).
// Evidence: 5 structural variants all ~12-13 ms -> per-round dependency chain
// (tanh -> publish/halting DPP -> barrier -> LDS-read -> fma chain) is the
// floor, not issue count or LDS bandwidth.
//  - Quad accumulators/row (8 total): fma dep chain 16 -> 8 deep.
//  - plds read hoisted BEFORE matvec's 16 ds_reads: halting-sigmoid chain
//    overlaps matvec instead of trailing it.
//  - 2-deep U prefetch ring (k_u's U lands in remote-XCD L2; 1-step prefetch
//    barely covers the ~600-900cy miss); next (un+wl2) precomputed off-path.
//  - Otherwise byte-identical to round 14: 2-row x 64-col lanes, quad
//    xor1+xor2 reduce, Z-linearity (no h publication), 2 barriers/timestep,
//    branchless rounds 0-1 + rare uniform rounds 2-3, L2E prefolds,
//    lgkmcnt-only barrier.
// ws = 8.45 MB (AccS aliases U in place; ws_size 16 MiB).

#define T_  8192
#define IO_ 32
#define H_  256

typedef __attribute__((ext_vector_type(2))) float v2f;

template<int CTRL>
__device__ __forceinline__ float dpp_addf(float x) {
    int xi = __builtin_bit_cast(int, x);
    int d = __builtin_amdgcn_update_dpp(xi, xi, CTRL, 0xF, 0xF, false);
    return x + __builtin_bit_cast(float, d);
}
// LDS-only barrier: flush DS ops, sync, do NOT drain vmcnt (global prefetch
// and fire-and-forget stores stay in flight).
__device__ __forceinline__ void bar_lds() {
    asm volatile("s_waitcnt lgkmcnt(0)\n\ts_barrier" ::: "memory");
    __builtin_amdgcn_sched_barrier(0);
}

// ---------------- k_prep: WxpT[io][h] = (Wx[:,:H]@Wp)^T, c = Wx[:,:H]@bp + b
__global__ void k_prep(const float* __restrict__ Wx,
                       const float* __restrict__ Wp,
                       const float* __restrict__ bp,
                       const float* __restrict__ b,
                       float* __restrict__ WxpT, float* __restrict__ cvec) {
    int h = blockIdx.x;           // 0..255
    int t = threadIdx.x;          // 0..63
    __shared__ float wxrow[H_];
    for (int j = t; j < H_; j += 64) wxrow[j] = Wx[h * (H_ + 1) + j];
    __syncthreads();
    if (t < IO_) {
        float acc = 0.0f;
        for (int j = 0; j < H_; ++j) acc += wxrow[j] * Wp[j * IO_ + t];
        WxpT[t * H_ + h] = acc;
    } else if (t == IO_) {
        float acc = b[h];
        for (int j = 0; j < H_; ++j) acc += wxrow[j] * bp[j];
        cvec[h] = acc;
    }
}

// ---------------- k_u: U[t][h] = (WxpT^T x_t + c) * 2*log2(e) ----------------
__global__ void k_u(const float* __restrict__ x,
                    const float* __restrict__ WxpT,
                    const float* __restrict__ cvec,
                    float* __restrict__ U) {
    int t0 = blockIdx.x * 8;
    int tid = threadIdx.x;        // 256
    __shared__ float xsf[8 * IO_];
    xsf[tid] = x[(size_t)t0 * IO_ + tid];
    __syncthreads();
    int h = tid;
    float base = cvec[h];
    const float L2E2 = 2.8853900817779268f;
    for (int tt = 0; tt < 8; ++tt) {
        float acc = base;
        #pragma unroll
        for (int io = 0; io < IO_; ++io)
            acc += WxpT[io * H_ + h] * xsf[tt * IO_ + io];
        U[(size_t)(t0 + tt) * H_ + h] = acc * L2E2;
    }
}

// ---------------- act_chain ----------------
__global__ __launch_bounds__(512, 2) void act_chain(
    const float* __restrict__ Ws,
    const float* __restrict__ Wx,
    const float* __restrict__ wh,
    const float* __restrict__ bh1,
    const float* __restrict__ h0,
    float* __restrict__ UAcc,
    float* __restrict__ cumArr,
    float* __restrict__ pc_out)
{
    __shared__ __align__(16) float sbuf[2][4 * 68];
    __shared__ __align__(16) float plds[2][8];

    const int tid = threadIdx.x;
    const int w   = tid >> 6;        // wave 0..7
    const int l   = tid & 63;
    const int rg  = l >> 2;          // row-group 0..15 (2 rows each)
    const int c   = l & 3;           // 64-col chunk 0..3
    const int rowbase = w * 32 + rg * 2;
    const int schunk  = rowbase >> 6;
    const int soff    = rowbase & 63;

    const float L2E  = 1.4426950408889634f;   // log2(e)
    const float L2E2 = 2.8853900817779268f;   // 2*log2(e)

    // Ws tile: 2 rows x 64 cols as v2f[2][32], prescaled by 2*log2(e)
    v2f wt[2][32];
    #pragma unroll
    for (int r = 0; r < 2; ++r) {
        const float4* src = (const float4*)(Ws + (size_t)(rowbase + r) * H_ + c * 64);
        #pragma unroll
        for (int q = 0; q < 16; ++q) {
            float4 f = src[q];
            wt[r][2 * q]     = (v2f){f.x * L2E2, f.y * L2E2};
            wt[r][2 * q + 1] = (v2f){f.z * L2E2, f.w * L2E2};
        }
    }

    v2f wl2, whp2;
    wl2.x  = Wx[(size_t)rowbase * (H_ + 1) + H_] * L2E2;       // first-step flag
    wl2.y  = Wx[(size_t)(rowbase + 1) * (H_ + 1) + H_] * L2E2;
    whp2.x = wh[rowbase]     * (-L2E);                          // sigmoid prescale
    whp2.y = wh[rowbase + 1] * (-L2E);
    const float bhp = -bh1[0] * L2E;
    const float thresh = 1.0f - 0.01f;

    // matvec of a 64-float column chunk + quad reduce.
    // Quad accumulators per row: 8-deep dependent-fma chain.
    auto matvec = [&](const float4* sp) -> v2f {
        v2f a0[4] = {{0.f,0.f},{0.f,0.f},{0.f,0.f},{0.f,0.f}};
        v2f a1[4] = {{0.f,0.f},{0.f,0.f},{0.f,0.f},{0.f,0.f}};
        #pragma unroll
        for (int q = 0; q < 16; ++q) {
            float4 f = sp[q];
            v2f sa = (v2f){f.x, f.y};
            v2f sb = (v2f){f.z, f.w};
            a0[q & 1]       = a0[q & 1]       + wt[0][2 * q]     * sa;
            a0[2 + (q & 1)] = a0[2 + (q & 1)] + wt[0][2 * q + 1] * sb;
            a1[q & 1]       = a1[q & 1]       + wt[1][2 * q]     * sa;
            a1[2 + (q & 1)] = a1[2 + (q & 1)] + wt[1][2 * q + 1] * sb;
        }
        v2f t0 = (a0[0] + a0[1]) + (a0[2] + a0[3]);
        v2f t1 = (a1[0] + a1[1]) + (a1[2] + a1[3]);
        float y0 = t0.x + t0.y;
        float y1 = t1.x + t1.y;
        y0 = dpp_addf<0xB1>(y0); y0 = dpp_addf<0x4E>(y0);   // quad xor1, xor2
        y1 = dpp_addf<0xB1>(y1); y1 = dpp_addf<0x4E>(y1);
        return (v2f){y0, y1};
    };

    // prologue: zh = scaled Ws @ h0 (chunk read direct from global)
    v2f zh;
    {
        float4 hbuf[16];
        const float4* hp = (const float4*)(h0 + c * 64);
        #pragma unroll
        for (int q = 0; q < 16; ++q) hbuf[q] = hp[q];
        zh = matvec(hbuf);
    }

    float pc = 0.0f;
    // 2-deep U prefetch ring
    v2f un  = *(const v2f*)(UAcc + rowbase);
    v2f un1 = *(const v2f*)(UAcc + (T_ > 1 ? H_ : 0) + rowbase);
    v2f uw0 = un + wl2;                       // round-0 input add, precomputed

    // one ponder round: s = tanh(in); publish; halting partial; barrier;
    // plds read first (halt chain overlaps matvec); matvec(s) -> z.
    auto round = [&](int WB, int PP, v2f in, v2f& z, float& p) -> v2f {
        float e0 = __builtin_amdgcn_exp2f(in.x);
        float e1 = __builtin_amdgcn_exp2f(in.y);
        float s0 = __builtin_fmaf(-2.0f, __builtin_amdgcn_rcpf(e0 + 1.0f), 1.0f);
        float s1 = __builtin_fmaf(-2.0f, __builtin_amdgcn_rcpf(e1 + 1.0f), 1.0f);
        if (c == 0) *(v2f*)(&sbuf[WB][schunk * 68 + soff]) = (v2f){s0, s1};
        // halting partial (quad-uniform): ror4+ror8 over row-groups,
        // bcast15+bcast31 -> lane63 = wave total (verified round 8)
        float part = __builtin_fmaf(whp2.x, s0, whp2.y * s1);
        part = dpp_addf<0x124>(part);   // row_ror:4
        part = dpp_addf<0x128>(part);   // row_ror:8
        part = dpp_addf<0x142>(part);   // row_bcast15
        part = dpp_addf<0x143>(part);   // row_bcast31
        if (l == 63) plds[PP][w] = part;
        bar_lds();
        float4 pa = *(const float4*)(&plds[PP][0]);     // issue before matvec
        float4 pb = *(const float4*)(&plds[PP][4]);     // reads: halt chain
        float dot = ((pa.x + pa.y) + (pa.z + pa.w)) +   // overlaps matvec
                    ((pb.x + pb.y) + (pb.z + pb.w));
        p = __builtin_amdgcn_rcpf(1.0f + __builtin_amdgcn_exp2f(dot + bhp));
        z = matvec((const float4*)(&sbuf[WB][c * 68]));
        return (v2f){s0, s1};
    };

    #pragma unroll 1
    for (int t = 0; t < T_; ++t) {
        const int tn2 = (t + 2 < T_) ? t + 2 : T_ - 1;
        const v2f un2 = *(const v2f*)(UAcc + (size_t)tn2 * H_ + rowbase);

        // rounds 0,1 unconditional straight-line
        v2f z0, z1;
        float p0, p1;
        v2f s0 = round(0, 0, zh + uw0, z0, p0);
        v2f s1 = round(1, 1, z0 + un,  z1, p1);

        bool  halt0  = p0 > thresh;
        float w0     = halt0 ? 1.0f : p0;
        bool  still1 = !halt0;
        float cum1   = w0;
        bool  halt1  = (cum1 + p1 > thresh);
        float w1     = still1 ? (halt1 ? 1.0f - cum1 : p1) : 0.0f;
        v2f   accs   = w0 * s0 + w1 * s1;
        v2f   zacc   = w0 * z0 + w1 * z1;
        float cum    = cum1 + w1;
        float nup    = still1 ? 2.0f : 1.0f;
        float rem    = halt0 ? 1.0f : (halt1 ? 1.0f - cum1 : 0.0f);

        if (still1 && !halt1) {               // rare, block-uniform: rounds 2,3
            v2f z2, z3;
            float p2, p3;
            v2f s2 = round(0, 0, z1 + un, z2, p2);
            bool  halt2 = (cum + p2 > thresh);
            float w2    = halt2 ? 1.0f - cum : p2;
            float rem2  = halt2 ? 1.0f - cum : 0.0f;
            accs = accs + w2 * s2;
            zacc = zacc + w2 * z2;
            float cum3   = cum + w2;
            bool  still3 = !halt2;
            v2f s3 = round(1, 1, z2 + un, z3, p3);
            float w3 = still3 ? (1.0f - cum3) : 0.0f;   // n==3 forces halt
            accs = accs + w3 * s3;
            zacc = zacc + w3 * z3;
            rem  = rem2 + w3;
            cum  = cum3 + w3;
            nup  = still3 ? 4.0f : 3.0f;
        }

        pc = (pc + nup + rem) * (1.0f / (float)T_);
        zh = zacc;                            // Z(h') by linearity — no LDS trip
        if (c == 0) *(v2f*)(UAcc + (size_t)t * H_ + rowbase) = accs;
        if (tid == 0) cumArr[t] = cum;
        un  = un1;                            // advance prefetch ring
        un1 = un2;
        uw0 = un + wl2;                       // next round-0 add, off-path
    }
    if (tid == 0) pc_out[0] = pc;
}

// ---------------- k_out: ys[t] = Wo@acc_s[t] + cum[t]*bo ----------------
__global__ void k_out(const float* __restrict__ AccS,
                      const float* __restrict__ Wo,
                      const float* __restrict__ bo,
                      const float* __restrict__ cumArr,
                      float* __restrict__ ys) {
    int t0 = blockIdx.x * 8;
    int tid = threadIdx.x;   // 256
    __shared__ float wo[IO_ * 257];
    __shared__ float as[8 * 260];
    for (int i = tid; i < IO_ * H_; i += 256) {
        int o = i / H_, h = i % H_;
        wo[o * 257 + h] = Wo[i];
    }
    for (int i = tid; i < 8 * H_; i += 256) {
        int tt = i / H_, h = i % H_;
        as[tt * 260 + h] = AccS[(size_t)t0 * H_ + i];
    }
    __syncthreads();
    int tt = tid >> 5, o = tid & 31;
    float acc = cumArr[t0 + tt] * bo[o];
    #pragma unroll 4
    for (int h = 0; h < H_; ++h) acc += wo[o * 257 + h] * as[tt * 260 + h];
    ys[(size_t)(t0 + tt) * IO_ + o] = acc;
}

extern "C" void kernel_launch(void* const* d_in, const int* in_sizes, int n_in,
                              void* d_out, int out_size, void* d_ws, size_t ws_size,
                              hipStream_t stream) {
    const float* x  = (const float*)d_in[0];
    const float* h0 = (const float*)d_in[1];
    const float* Wp = (const float*)d_in[2];
    const float* bp = (const float*)d_in[3];
    const float* Wx = (const float*)d_in[4];
    const float* Ws = (const float*)d_in[5];
    const float* b  = (const float*)d_in[6];
    const float* wh = (const float*)d_in[7];
    const float* bh = (const float*)d_in[8];
    const float* Wo = (const float*)d_in[9];
    const float* bo = (const float*)d_in[10];
    float* out = (float*)d_out;   // f32: ys[8192*32] then pc

    char* ws = (char*)d_ws;
    float* WxpT = (float*)ws;                                    //  32 KB
    float* cvec = (float*)(ws + 32768);                          //   1 KB
    float* cumA = (float*)(ws + 33792);                          //  32 KB
    float* UAcc = (float*)(ws + 66560);                          //   8 MB f32
    // total ws use: 8.45 MB (AccS aliases UAcc in place)

    k_prep<<<H_, 64, 0, stream>>>(Wx, Wp, bp, b, WxpT, cvec);
    k_u<<<T_ / 8, 256, 0, stream>>>(x, WxpT, cvec, UAcc);
    act_chain<<<1, 512, 0, stream>>>(Ws, Wx, wh, bh, h0, UAcc, cumA,
                                     out + (size_t)T_ * IO_);
    k_out<<<T_ / 8, 256, 0, stream>>>(UAcc, Wo, bo, cumA, out);
}